// Round 1
// baseline (1115.616 us; speedup 1.0000x reference)
//
#include <hip/hip_runtime.h>
#include <math.h>

#define N_PIX (512 * 512)      // 262144 pixels
#define NUM_CLASSES 150
#define CF 256                 // feature channels
#define CG 32                  // channels per block (channel group)
#define CGP 33                 // padded LDS stride: (lab*33+c)%32 = (lab+c)%32 -> spreads banks
#define PIX_PER_BLOCK 2048     // 262144 / 2048 = 128 pixel chunks
#define THREADS 256
#define EPS 1e-8f

// ---------------------------------------------------------------------------
// ws layout (floats):
//   [0, 76800)       sums: [2 tensors][150 classes][256 channels]
//   [76800, 77100)   counts: [2 tensors][150 classes]
// ---------------------------------------------------------------------------

__global__ __launch_bounds__(THREADS) void hist_kernel(
    const int* __restrict__ l_src, const int* __restrict__ l_trg,
    float* __restrict__ cnt) {
  const int* l = blockIdx.y ? l_trg : l_src;
  float* c = cnt + blockIdx.y * NUM_CLASSES;
  __shared__ int hist[NUM_CLASSES];
  for (int i = threadIdx.x; i < NUM_CLASSES; i += THREADS) hist[i] = 0;
  __syncthreads();
  for (int p = blockIdx.x * THREADS + threadIdx.x; p < N_PIX;
       p += gridDim.x * THREADS)
    atomicAdd(&hist[l[p]], 1);
  __syncthreads();
  for (int i = threadIdx.x; i < NUM_CLASSES; i += THREADS)
    if (hist[i]) unsafeAtomicAdd(&c[i], (float)hist[i]);
}

__global__ __launch_bounds__(THREADS) void scatter_kernel(
    const float* __restrict__ f_src, const float* __restrict__ f_trg,
    const int* __restrict__ l_src, const int* __restrict__ l_trg,
    float* __restrict__ sums) {
  const int tensor = blockIdx.z;
  const float* __restrict__ f = tensor ? f_trg : f_src;
  const int* __restrict__ lab = tensor ? l_trg : l_src;
  float* __restrict__ out = sums + tensor * (NUM_CLASSES * CF);

  const int c0 = blockIdx.y * CG;
  const int p0 = blockIdx.x * PIX_PER_BLOCK;

  __shared__ float acc[NUM_CLASSES * CGP];  // ~19.8 KB
  for (int i = threadIdx.x; i < NUM_CLASSES * CGP; i += THREADS) acc[i] = 0.f;
  __syncthreads();

  const float* __restrict__ fb = f + (size_t)c0 * N_PIX;
  for (int p = p0 + threadIdx.x; p < p0 + PIX_PER_BLOCK; p += THREADS) {
    const int lb = lab[p];
    float* a = &acc[lb * CGP];
#pragma unroll
    for (int cl = 0; cl < CG; ++cl) {
      // coalesced across lanes: consecutive p for fixed channel
      atomicAdd(&a[cl], fb[(size_t)cl * N_PIX + p]);
    }
  }
  __syncthreads();

  // flush LDS partials to global sums[cls*CF + c0 + cl]
  for (int i = threadIdx.x; i < NUM_CLASSES * CG; i += THREADS) {
    const int cls = i / CG;
    const int cl = i % CG;
    const float v = acc[cls * CGP + cl];
    if (v != 0.f) unsafeAtomicAdd(&out[cls * CF + c0 + cl], v);
  }
}

__global__ __launch_bounds__(THREADS) void finalize_kernel(
    const float* __restrict__ sums, const float* __restrict__ cnt,
    float* __restrict__ out) {
  const float* ss = sums;
  const float* st = sums + NUM_CLASSES * CF;
  const float* cs = cnt;
  const float* ct = cnt + NUM_CLASSES;
  float acc = 0.f;
  for (int i = threadIdx.x; i < NUM_CLASSES * CF; i += THREADS) {
    const int cls = i >> 8;  // CF == 256
    const float d = ss[i] / (cs[cls] + EPS) - st[i] / (ct[cls] + EPS);
    acc += d * d;
  }
#pragma unroll
  for (int off = 32; off > 0; off >>= 1) acc += __shfl_down(acc, off, 64);
  __shared__ float red[THREADS / 64];
  const int lane = threadIdx.x & 63;
  const int wid = threadIdx.x >> 6;
  if (lane == 0) red[wid] = acc;
  __syncthreads();
  if (threadIdx.x == 0) {
    float t = 0.f;
#pragma unroll
    for (int w = 0; w < THREADS / 64; ++w) t += red[w];
    out[0] = sqrtf(t);
  }
}

extern "C" void kernel_launch(void* const* d_in, const int* in_sizes, int n_in,
                              void* d_out, int out_size, void* d_ws,
                              size_t ws_size, hipStream_t stream) {
  const float* f_src = (const float*)d_in[0];
  const float* f_trg = (const float*)d_in[1];
  const int* l_src = (const int*)d_in[2];
  const int* l_trg = (const int*)d_in[3];
  float* out = (float*)d_out;

  float* sums = (float*)d_ws;                    // 2 * 150 * 256 floats
  float* cnt = sums + 2 * NUM_CLASSES * CF;      // 2 * 150 floats

  const size_t zero_bytes =
      (size_t)(2 * NUM_CLASSES * CF + 2 * NUM_CLASSES) * sizeof(float);
  hipMemsetAsync(d_ws, 0, zero_bytes, stream);

  hipLaunchKernelGGL(hist_kernel, dim3(64, 2), dim3(THREADS), 0, stream,
                     l_src, l_trg, cnt);
  hipLaunchKernelGGL(scatter_kernel,
                     dim3(N_PIX / PIX_PER_BLOCK, CF / CG, 2), dim3(THREADS), 0,
                     stream, f_src, f_trg, l_src, l_trg, sums);
  hipLaunchKernelGGL(finalize_kernel, dim3(1), dim3(THREADS), 0, stream, sums,
                     cnt, out);
}

// Round 2
// 1050.702 us; speedup vs baseline: 1.0618x; 1.0618x over previous
//
#include <hip/hip_runtime.h>
#include <math.h>

#define N_PIX (512 * 512)      // 262144 pixels
#define NQ (N_PIX / 4)         // 65536 pixel-quads (float4 granularity)
#define NUM_CLASSES 150
#define CF 256                 // feature channels
#define CG 32                  // channels per block (channel group)
#define CGP 33                 // padded LDS stride: bank = (lab + c) % 32 -> spread by label
#define QUADS_PER_BLOCK 512    // 65536 / 512 = 128 pixel chunks; 2 passes of 256 threads
#define THREADS 256
#define EPS 1e-8f

// ---------------------------------------------------------------------------
// ws layout (floats):
//   [0, 76800)       sums: [2 tensors][150 classes][256 channels]
//   [76800, 77100)   counts: [2 tensors][150 classes]
// ---------------------------------------------------------------------------

__global__ __launch_bounds__(THREADS, 6) void scatter_kernel(
    const float* __restrict__ f_src, const float* __restrict__ f_trg,
    const int* __restrict__ l_src, const int* __restrict__ l_trg,
    float* __restrict__ sums, float* __restrict__ cnt) {
  const int tensor = blockIdx.z;
  const float* __restrict__ f = tensor ? f_trg : f_src;
  const int* __restrict__ lab = tensor ? l_trg : l_src;
  float* __restrict__ out = sums + tensor * (NUM_CLASSES * CF);
  float* __restrict__ cn = cnt + tensor * NUM_CLASSES;

  const int c0 = blockIdx.y * CG;
  const int q0 = blockIdx.x * QUADS_PER_BLOCK;
  const bool do_count = (blockIdx.y == 0);

  __shared__ float acc[NUM_CLASSES * CGP];  // ~19.8 KB
  __shared__ int chist[NUM_CLASSES];
  for (int i = threadIdx.x; i < NUM_CLASSES * CGP; i += THREADS) acc[i] = 0.f;
  if (do_count)
    for (int i = threadIdx.x; i < NUM_CLASSES; i += THREADS) chist[i] = 0;
  __syncthreads();

  // float4 view of this channel-group's feature rows: fb4[cl * NQ + q]
  const float4* __restrict__ fb4 =
      (const float4*)f + (size_t)c0 * NQ;
  const int4* __restrict__ lab4 = (const int4*)lab;

  for (int q = q0 + threadIdx.x; q < q0 + QUADS_PER_BLOCK; q += THREADS) {
    const int4 lb = lab4[q];
    float* __restrict__ a0 = &acc[lb.x * CGP];
    float* __restrict__ a1 = &acc[lb.y * CGP];
    float* __restrict__ a2 = &acc[lb.z * CGP];
    float* __restrict__ a3 = &acc[lb.w * CGP];
    if (do_count) {
      atomicAdd(&chist[lb.x], 1);
      atomicAdd(&chist[lb.y], 1);
      atomicAdd(&chist[lb.z], 1);
      atomicAdd(&chist[lb.w], 1);
    }
#pragma unroll
    for (int sub = 0; sub < CG / 8; ++sub) {
      float4 v[8];
      // Batch 8 independent 16B loads FIRST (program order!), so the compiler
      // issues them back-to-back and amortizes HBM latency 8x. Do NOT
      // interleave with the atomics below: loads can't hoist past atomics.
#pragma unroll
      for (int c = 0; c < 8; ++c)
        v[c] = fb4[(size_t)(sub * 8 + c) * NQ + q];
#pragma unroll
      for (int c = 0; c < 8; ++c) {
        const int cc = sub * 8 + c;
        atomicAdd(&a0[cc], v[c].x);
        atomicAdd(&a1[cc], v[c].y);
        atomicAdd(&a2[cc], v[c].z);
        atomicAdd(&a3[cc], v[c].w);
      }
    }
  }
  __syncthreads();

  // flush LDS partials to global sums[cls*CF + c0 + cl]
  for (int i = threadIdx.x; i < NUM_CLASSES * CG; i += THREADS) {
    const int cls = i / CG;
    const int cl = i % CG;
    const float v = acc[cls * CGP + cl];
    if (v != 0.f) unsafeAtomicAdd(&out[cls * CF + c0 + cl], v);
  }
  if (do_count)
    for (int i = threadIdx.x; i < NUM_CLASSES; i += THREADS)
      if (chist[i]) unsafeAtomicAdd(&cn[i], (float)chist[i]);
}

#define FTHREADS 1024
__global__ __launch_bounds__(FTHREADS) void finalize_kernel(
    const float* __restrict__ sums, const float* __restrict__ cnt,
    float* __restrict__ out) {
  const float* ss = sums;
  const float* st = sums + NUM_CLASSES * CF;
  const float* cs = cnt;
  const float* ct = cnt + NUM_CLASSES;
  float acc = 0.f;
  for (int i = threadIdx.x; i < NUM_CLASSES * CF; i += FTHREADS) {
    const int cls = i >> 8;  // CF == 256
    const float d = ss[i] / (cs[cls] + EPS) - st[i] / (ct[cls] + EPS);
    acc += d * d;
  }
#pragma unroll
  for (int off = 32; off > 0; off >>= 1) acc += __shfl_down(acc, off, 64);
  __shared__ float red[FTHREADS / 64];
  const int lane = threadIdx.x & 63;
  const int wid = threadIdx.x >> 6;
  if (lane == 0) red[wid] = acc;
  __syncthreads();
  if (threadIdx.x == 0) {
    float t = 0.f;
#pragma unroll
    for (int w = 0; w < FTHREADS / 64; ++w) t += red[w];
    out[0] = sqrtf(t);
  }
}

extern "C" void kernel_launch(void* const* d_in, const int* in_sizes, int n_in,
                              void* d_out, int out_size, void* d_ws,
                              size_t ws_size, hipStream_t stream) {
  const float* f_src = (const float*)d_in[0];
  const float* f_trg = (const float*)d_in[1];
  const int* l_src = (const int*)d_in[2];
  const int* l_trg = (const int*)d_in[3];
  float* out = (float*)d_out;

  float* sums = (float*)d_ws;                    // 2 * 150 * 256 floats
  float* cnt = sums + 2 * NUM_CLASSES * CF;      // 2 * 150 floats

  const size_t zero_bytes =
      (size_t)(2 * NUM_CLASSES * CF + 2 * NUM_CLASSES) * sizeof(float);
  hipMemsetAsync(d_ws, 0, zero_bytes, stream);

  hipLaunchKernelGGL(scatter_kernel,
                     dim3(NQ / QUADS_PER_BLOCK, CF / CG, 2), dim3(THREADS), 0,
                     stream, f_src, f_trg, l_src, l_trg, sums, cnt);
  hipLaunchKernelGGL(finalize_kernel, dim3(1), dim3(FTHREADS), 0, stream, sums,
                     cnt, out);
}